// Round 13
// baseline (805.638 us; speedup 1.0000x reference)
//
#include <hip/hip_runtime.h>
#include <hip/hip_bf16.h>
#include <math.h>

// ---------------------------------------------------------------------------
// SpatialTransformer block. R12: LDS-tiled coalesced weight transpose in the
// preamble; prefetch depth-2 ping-pong MFMA GEMMs.
// B=8, C=320, H=W=32 (HW=1024), HEADS=8, DHEAD=40, CTX=77x768, FF_INNER=1280.
// ---------------------------------------------------------------------------

#define Bsz   8
#define Cch   320
#define HW    1024
#define NTOK  (Bsz*HW)          // 8192
#define HEADS 8
#define DHEAD 40
#define CTXL  77
#define CTXD  768
#define FFI   1280
#define MCTX  (Bsz*CTXL)        // 616
#define MCTXP 640               // padded rows for ctx GEMM

typedef unsigned short u16;
typedef unsigned long long u64;
typedef __attribute__((ext_vector_type(8))) u16    u16x8;
typedef __attribute__((ext_vector_type(8))) __bf16 bf16x8;
typedef __attribute__((ext_vector_type(4))) float  f32x4;

__device__ inline u16 f2b(float f) {            // fp32 -> bf16 RNE
    unsigned u = __float_as_uint(f);
    return (u16)((u + 0x7FFFu + ((u >> 16) & 1u)) >> 16);
}

// ------------------------------------------- GroupNorm pass 1: statistics
__global__ __launch_bounds__(256) void gn_stats(
    const float* __restrict__ x, const float* __restrict__ scale,
    const float* __restrict__ bias, float* __restrict__ gnA,
    float* __restrict__ gnB)
{
    int blk = blockIdx.x;           // b*32 + g
    int b = blk >> 5, g = blk & 31;
    int tid = threadIdx.x;
    __shared__ float rs[256], rq[256];
    const float4* xg = (const float4*)(x + ((size_t)b*Cch + g*10)*HW);
    float s = 0.f, q = 0.f;
    #pragma unroll
    for (int i = 0; i < 10; ++i) {
        float4 v = xg[tid + i*256];
        s += v.x + v.y + v.z + v.w;
        q += v.x*v.x + v.y*v.y + v.z*v.z + v.w*v.w;
    }
    rs[tid] = s; rq[tid] = q; __syncthreads();
    for (int off = 128; off > 0; off >>= 1) {
        if (tid < off) { rs[tid] += rs[tid+off]; rq[tid] += rq[tid+off]; }
        __syncthreads();
    }
    if (tid < 10) {
        float mean = rs[0] * (1.f/10240.f);
        float var  = rq[0] * (1.f/10240.f) - mean*mean;
        float inv  = rsqrtf(var + 1e-6f);
        int ch = g*10 + tid;
        float a = inv * scale[ch];
        gnA[b*Cch + ch] = a;
        gnB[b*Cch + ch] = bias[ch] - mean*a;
    }
}

// ------------------------- GroupNorm pass 2: normalize + CHW->token-major
__global__ __launch_bounds__(256) void gn_apply(
    const float* __restrict__ x, const float* __restrict__ gnA,
    const float* __restrict__ gnB, u16* __restrict__ out)
{
    __shared__ u16 T[64*72];
    const int tid = threadIdx.x;
    const int c0 = blockIdx.x * 64;
    const int p0 = blockIdx.y * 64;
    const int b  = blockIdx.z;
    for (int e = tid; e < 512; e += 256) {
        int r = e >> 3, ch = e & 7;
        const float* src = x + ((size_t)(b*Cch + c0 + r))*HW + p0 + ch*8;
        float a  = gnA[b*Cch + c0 + r];
        float bb = gnB[b*Cch + c0 + r];
        float4 v0 = *(const float4*)src;
        float4 v1 = *(const float4*)(src + 4);
        u16x8 val;
        val[0] = f2b(v0.x*a + bb); val[1] = f2b(v0.y*a + bb);
        val[2] = f2b(v0.z*a + bb); val[3] = f2b(v0.w*a + bb);
        val[4] = f2b(v1.x*a + bb); val[5] = f2b(v1.y*a + bb);
        val[6] = f2b(v1.z*a + bb); val[7] = f2b(v1.w*a + bb);
        *(u16x8*)&T[r*72 + (ch ^ (r & 7))*8] = val;
    }
    __syncthreads();
    for (int e = tid; e < 4096; e += 256) {
        int p = e >> 6, c = e & 63;
        u16 v = T[c*72 + (((p >> 3) ^ (c & 7))*8) + (p & 7)];
        out[((size_t)(b*HW + p0 + p))*Cch + c0 + c] = v;
    }
}

// ------------------------------------------------------- LayerNorm -> bf16
__global__ __launch_bounds__(256) void layernorm_kernel(
    const float* __restrict__ in, const float* __restrict__ s,
    const float* __restrict__ bgain, u16* __restrict__ out)
{
    int t = blockIdx.x*4 + (threadIdx.x >> 6);
    int lane = threadIdx.x & 63;
    const float* row = in + (size_t)t*Cch;
    float v[5];
    float sum = 0.f, sq = 0.f;
    #pragma unroll
    for (int i = 0; i < 5; ++i) {
        v[i] = row[lane + 64*i];
        sum += v[i]; sq += v[i]*v[i];
    }
    #pragma unroll
    for (int off = 32; off > 0; off >>= 1) {
        sum += __shfl_xor(sum, off);
        sq  += __shfl_xor(sq,  off);
    }
    float mean = sum * (1.f/320.f);
    float var  = sq  * (1.f/320.f) - mean*mean;
    float inv  = rsqrtf(var + 1e-5f);
    u16* orow = out + (size_t)t*Cch;
    #pragma unroll
    for (int i = 0; i < 5; ++i) {
        int c = lane + 64*i;
        orow[c] = f2b((v[i]-mean)*inv*s[c] + bgain[c]);
    }
}

// ------------------------------- fused preamble: weights + ctx + mask bits
// Weights: fp32 [K,N] -> bf16 [N,K]*scl via 64x64 LDS tile (coalesced both sides)
struct WDesc { const float* src; u16* dst; int K; int N; int tiles; float scl; };
struct WPack { WDesc w[12]; };

#define WT_TILES 620
#define CTXBLK   240     // 640*768 / 2048

__global__ __launch_bounds__(256) void preamble(
    WPack p, const float* __restrict__ ctxsrc, u16* __restrict__ ctxdst,
    const void* __restrict__ vis, const void* __restrict__ v2t,
    u64* __restrict__ bvis, u64* __restrict__ bv2t)
{
    __shared__ u16 T[64*72];
    int blk = blockIdx.x;
    int tid = threadIdx.x;
    if (blk < WT_TILES) {                      // tiled weight transpose
        int t = blk;
        #pragma unroll
        for (int i = 0; i < 12; ++i) {
            int nt = p.w[i].tiles;
            if (t < nt) {
                const int K = p.w[i].K, N = p.w[i].N;
                const int ntN = N >> 6;
                const int tk = t / ntN, tn = t - tk*ntN;
                const float scl = p.w[i].scl;
                const float* src = p.w[i].src;
                u16* dst = p.w[i].dst;
                for (int e = tid; e < 512; e += 256) {
                    int r = e >> 3, ch = e & 7;
                    const float* sp = src + (size_t)(tk*64 + r)*N + tn*64 + ch*8;
                    float4 v0 = *(const float4*)sp;
                    float4 v1 = *(const float4*)(sp + 4);
                    u16x8 val;
                    val[0] = f2b(v0.x*scl); val[1] = f2b(v0.y*scl);
                    val[2] = f2b(v0.z*scl); val[3] = f2b(v0.w*scl);
                    val[4] = f2b(v1.x*scl); val[5] = f2b(v1.y*scl);
                    val[6] = f2b(v1.z*scl); val[7] = f2b(v1.w*scl);
                    *(u16x8*)&T[r*72 + (ch ^ (r & 7))*8] = val;
                }
                __syncthreads();
                for (int e = tid; e < 4096; e += 256) {
                    int n = e >> 6, k = e & 63;
                    u16 v = T[k*72 + (((n >> 3) ^ (k & 7))*8) + (n & 7)];
                    dst[(size_t)(tn*64 + n)*K + tk*64 + k] = v;
                }
                return;
            }
            t -= nt;
        }
        return;
    }
    if (blk < WT_TILES + CTXBLK) {             // ctx fp32 -> bf16 (padded)
        int idx = (blk - WT_TILES)*2048 + tid*8;
        int r = idx / CTXD;
        u16x8 val = {};
        if (r < MCTX) {
            float4 v0 = *(const float4*)(ctxsrc + idx);
            float4 v1 = *(const float4*)(ctxsrc + idx + 4);
            val[0] = f2b(v0.x); val[1] = f2b(v0.y);
            val[2] = f2b(v0.z); val[3] = f2b(v0.w);
            val[4] = f2b(v1.x); val[5] = f2b(v1.y);
            val[6] = f2b(v1.z); val[7] = f2b(v1.w);
        }
        *(u16x8*)(ctxdst + idx) = val;
        return;
    }
    // mask -> bit words; dtype probed from vis[0..4096)
    __shared__ int any;
    if (tid == 0) any = 0;
    __syncthreads();
    const unsigned char* probe = (const unsigned char*)vis;
    for (int i = tid; i < 4096; i += 256)
        if ((i & 3) && probe[i]) any = 1;
    __syncthreads();
    const int isU8 = any;
    int mb = blk - WT_TILES - CTXBLK;          // 0..4095
    const void* mask; u64* bits; int Lkv, nw;
    if (mb < 2048) { mask = vis; bits = bvis; Lkv = HW;   nw = 16; }
    else           { mask = v2t; bits = bv2t; Lkv = CTXL; nw = 2; mb -= 2048; }
    const int wv = tid >> 6, lane = tid & 63;
    const int row = mb*4 + wv;
    const unsigned char* m8  = (const unsigned char*)mask;
    const int*           m32 = (const int*)mask;
    const size_t base = (size_t)row * Lkv;
    for (int w = 0; w < nw; ++w) {
        int j = w*64 + lane;
        bool on = (j < Lkv) && (isU8 ? (m8[base+j] != 0) : (m32[base+j] != 0));
        u64 word = __ballot(on);
        if (lane == 0) bits[(size_t)row*nw + w] = word;
    }
}

// ------------------- bf16 MFMA GEMM, ping-pong dbuf, prefetch depth 2
__global__ __launch_bounds__(256) void gemm_bf16(
    const u16* __restrict__ A, const u16* __restrict__ Wt,
    const float* __restrict__ bias, const float* __restrict__ res,
    float* __restrict__ out, u16* __restrict__ out_bf, int M, int N, int K)
{
    __shared__ u16 As[2][128*40];
    __shared__ u16 Bs[2][64*40];
    const int tid  = threadIdx.x;
    const int lane = tid & 63;
    const int w    = tid >> 6;
    const int m0   = blockIdx.y * 128;
    const int n0   = blockIdx.x * 64;
    const int fr   = lane & 15, fg = lane >> 4;
    const int ar   = tid >> 2, ac = tid & 3;

    const u16* pa0 = A  + (size_t)(m0 + ar)*K      + ac*8;
    const u16* pa1 = A  + (size_t)(m0 + ar + 64)*K + ac*8;
    const u16* pb  = Wt + (size_t)(n0 + ar)*K      + ac*8;
    const int nk = K >> 5;

    *(u16x8*)&As[0][ar*40 + ac*8]      = *(const u16x8*)pa0;
    *(u16x8*)&As[0][(ar+64)*40 + ac*8] = *(const u16x8*)pa1;
    *(u16x8*)&Bs[0][ar*40 + ac*8]      = *(const u16x8*)pb;
    u16x8 ra0[2], ra1[2], rb[2];
    if (nk > 1) {
        ra0[1] = *(const u16x8*)(pa0 + 32);
        ra1[1] = *(const u16x8*)(pa1 + 32);
        rb[1]  = *(const u16x8*)(pb  + 32);
    }
    if (nk > 2) {
        ra0[0] = *(const u16x8*)(pa0 + 64);
        ra1[0] = *(const u16x8*)(pa1 + 64);
        rb[0]  = *(const u16x8*)(pb  + 64);
    }

    f32x4 acc[2][4] = {};
    for (int i = 0; i < nk; ++i) {
        __syncthreads();
        const int cur = i & 1;
        if (i + 1 < nk) {
            const int s = (i + 1) & 1;
            *(u16x8*)&As[cur^1][ar*40 + ac*8]      = ra0[s];
            *(u16x8*)&As[cur^1][(ar+64)*40 + ac*8] = ra1[s];
            *(u16x8*)&Bs[cur^1][ar*40 + ac*8]      = rb[s];
            if (i + 3 < nk) {
                const int f = (i + 3) & 1;
                ra0[f] = *(const u16x8*)(pa0 + 32*(i+3));
                ra1[f] = *(const u16x8*)(pa1 + 32*(i+3));
                rb[f]  = *(const u16x8*)(pb  + 32*(i+3));
            }
        }
        bf16x8 a0 = *(const bf16x8*)&As[cur][(w*32      + fr)*40 + fg*8];
        bf16x8 a1 = *(const bf16x8*)&As[cur][(w*32 + 16 + fr)*40 + fg*8];
        #pragma unroll
        for (int nt = 0; nt < 4; ++nt) {
            bf16x8 b = *(const bf16x8*)&Bs[cur][(nt*16 + fr)*40 + fg*8];
            acc[0][nt] = __builtin_amdgcn_mfma_f32_16x16x32_bf16(a0, b, acc[0][nt], 0, 0, 0);
            acc[1][nt] = __builtin_amdgcn_mfma_f32_16x16x32_bf16(a1, b, acc[1][nt], 0, 0, 0);
        }
    }
    #pragma unroll
    for (int at = 0; at < 2; ++at) {
        #pragma unroll
        for (int nt = 0; nt < 4; ++nt) {
            int gn = n0 + nt*16 + fr;
            float bv = bias ? bias[gn] : 0.f;
            #pragma unroll
            for (int i = 0; i < 4; ++i) {
                int gm = m0 + w*32 + at*16 + fg*4 + i;
                float v = acc[at][nt][i] + bv;
                if (res) v += res[(size_t)gm*N + gn];
                if (out) out[(size_t)gm*N + gn] = v;
                if (out_bf) out_bf[(size_t)gm*N + gn] = f2b(v);
            }
        }
    }
}

// ------------------- proj_out GEMM + transpose + residual, depth-2 dbuf
__global__ __launch_bounds__(256) void gemm_pout(
    const u16* __restrict__ A, const u16* __restrict__ Wt,
    const float* __restrict__ bias, const float* __restrict__ x,
    float* __restrict__ out, int K)
{
    __shared__ u16 As[2][128*40];
    __shared__ u16 Bs[2][64*40];
    const int tid  = threadIdx.x;
    const int lane = tid & 63;
    const int w    = tid >> 6;
    const int m0   = blockIdx.y * 128;
    const int n0   = blockIdx.x * 64;
    const int fr   = lane & 15, fg = lane >> 4;
    const int ar   = tid >> 2, ac = tid & 3;

    const u16* pa0 = A  + (size_t)(m0 + ar)*K      + ac*8;
    const u16* pa1 = A  + (size_t)(m0 + ar + 64)*K + ac*8;
    const u16* pb  = Wt + (size_t)(n0 + ar)*K      + ac*8;
    const int nk = K >> 5;

    *(u16x8*)&As[0][ar*40 + ac*8]      = *(const u16x8*)pa0;
    *(u16x8*)&As[0][(ar+64)*40 + ac*8] = *(const u16x8*)pa1;
    *(u16x8*)&Bs[0][ar*40 + ac*8]      = *(const u16x8*)pb;
    u16x8 ra0[2], ra1[2], rb[2];
    if (nk > 1) {
        ra0[1] = *(const u16x8*)(pa0 + 32);
        ra1[1] = *(const u16x8*)(pa1 + 32);
        rb[1]  = *(const u16x8*)(pb  + 32);
    }
    if (nk > 2) {
        ra0[0] = *(const u16x8*)(pa0 + 64);
        ra1[0] = *(const u16x8*)(pa1 + 64);
        rb[0]  = *(const u16x8*)(pb  + 64);
    }

    f32x4 acc[2][4] = {};
    for (int i = 0; i < nk; ++i) {
        __syncthreads();
        const int cur = i & 1;
        if (i + 1 < nk) {
            const int s = (i + 1) & 1;
            *(u16x8*)&As[cur^1][ar*40 + ac*8]      = ra0[s];
            *(u16x8*)&As[cur^1][(ar+64)*40 + ac*8] = ra1[s];
            *(u16x8*)&Bs[cur^1][ar*40 + ac*8]      = rb[s];
            if (i + 3 < nk) {
                const int f = (i + 3) & 1;
                ra0[f] = *(const u16x8*)(pa0 + 32*(i+3));
                ra1[f] = *(const u16x8*)(pa1 + 32*(i+3));
                rb[f]  = *(const u16x8*)(pb  + 32*(i+3));
            }
        }
        bf16x8 a0 = *(const bf16x8*)&As[cur][(w*32      + fr)*40 + fg*8];
        bf16x8 a1 = *(const bf16x8*)&As[cur][(w*32 + 16 + fr)*40 + fg*8];
        #pragma unroll
        for (int nt = 0; nt < 4; ++nt) {
            bf16x8 b = *(const bf16x8*)&Bs[cur][(nt*16 + fr)*40 + fg*8];
            acc[0][nt] = __builtin_amdgcn_mfma_f32_16x16x32_bf16(a0, b, acc[0][nt], 0, 0, 0);
            acc[1][nt] = __builtin_amdgcn_mfma_f32_16x16x32_bf16(a1, b, acc[1][nt], 0, 0, 0);
        }
    }
    #pragma unroll
    for (int at = 0; at < 2; ++at) {
        #pragma unroll
        for (int nt = 0; nt < 4; ++nt) {
            int gn = n0 + nt*16 + fr;
            float bv = bias[gn];
            int gm0 = m0 + w*32 + at*16 + fg*4;      // multiple of 4
            int b   = gm0 >> 10;
            int p   = gm0 & (HW-1);
            size_t o = ((size_t)(b*Cch + gn))*HW + p;
            f32x4 xv = *(const f32x4*)&x[o];
            f32x4 vv;
            #pragma unroll
            for (int i = 0; i < 4; ++i) vv[i] = acc[at][nt][i] + bv + xv[i];
            *(f32x4*)&out[o] = vv;
        }
    }
}

// ------------------- ctx K/V batched MFMA GEMM (bf16), depth-2 dbuf
__global__ __launch_bounds__(256) void ctx_kv_gemm(
    const u16* __restrict__ ctx, const u16* __restrict__ wk,
    const u16* __restrict__ wv, u16* __restrict__ kout, u16* __restrict__ vout)
{
    __shared__ u16 As[2][64*40];
    __shared__ u16 Bs[2][64*40];
    const int tid  = threadIdx.x;
    const int lane = tid & 63;
    const int w    = tid >> 6;
    const int m0   = blockIdx.y * 64;
    const int n0   = blockIdx.x * 64;
    const u16* Wt  = blockIdx.z ? wv : wk;
    u16* outp      = blockIdx.z ? vout : kout;
    const int fr   = lane & 15, fg = lane >> 4;
    const int ar   = tid >> 2, ac = tid & 3;

    const u16* pa = ctx + (size_t)(m0 + ar)*CTXD + ac*8;
    const u16* pb = Wt  + (size_t)(n0 + ar)*CTXD + ac*8;
    const int nk = CTXD >> 5;    // 24

    *(u16x8*)&As[0][ar*40 + ac*8] = *(const u16x8*)pa;
    *(u16x8*)&Bs[0][ar*40 + ac*8] = *(const u16x8*)pb;
    u16x8 ra[2], rb[2];
    ra[1] = *(const u16x8*)(pa + 32);
    rb[1] = *(const u16x8*)(pb + 32);
    ra[0] = *(const u16x8*)(pa + 64);
    rb[0] = *(const u16x8*)(pb + 64);

    f32x4 acc[4] = {};
    for (int i = 0; i < nk; ++i) {
        __syncthreads();
        const int cur = i & 1;
        if (i + 1 < nk) {
            const int s = (i + 1) & 1;
            *(u16x8*)&As[cur^1][ar*40 + ac*8] = ra[s];
            *(u16x8*)&Bs[cur^1][ar*40 + ac*8] = rb[s];
            if (i + 3 < nk) {
                const int f = (i + 3) & 1;
                ra[f] = *(const u16x8*)(pa + 32*(i+3));
                rb[f] = *(const u16x8*)(pb + 32*(i+3));
            }
        }
        bf16x8 a = *(const bf16x8*)&As[cur][(w*16 + fr)*40 + fg*8];
        #pragma unroll
        for (int nt = 0; nt < 4; ++nt) {
            bf16x8 b = *(const bf16x8*)&Bs[cur][(nt*16 + fr)*40 + fg*8];
            acc[nt] = __builtin_amdgcn_mfma_f32_16x16x32_bf16(a, b, acc[nt], 0, 0, 0);
        }
    }
    #pragma unroll
    for (int nt = 0; nt < 4; ++nt) {
        int gn = n0 + nt*16 + fr;
        #pragma unroll
        for (int i = 0; i < 4; ++i) {
            int gm = m0 + w*16 + fg*4 + i;
            if (gm < MCTX)
                outp[(size_t)gm*Cch + gn] = f2b(acc[nt][i]);
        }
    }
}

// --------------------- GEGLU fused MFMA GEMM (bf16), depth-2 dbuf
__global__ __launch_bounds__(256) void geglu_bf16(
    const u16* __restrict__ A, const u16* __restrict__ Wt,
    const float* __restrict__ b1, u16* __restrict__ out, int M, int K)
{
    __shared__ u16 As[2][128*40];
    __shared__ u16 Ba[2][64*40];
    __shared__ u16 Bg[2][64*40];
    const int tid  = threadIdx.x;
    const int lane = tid & 63;
    const int w    = tid >> 6;
    const int m0   = blockIdx.y * 128;
    const int n0   = blockIdx.x * 64;
    const int fr   = lane & 15, fg = lane >> 4;
    const int ar   = tid >> 2, ac = tid & 3;

    const u16* pa0 = A  + (size_t)(m0 + ar)*K      + ac*8;
    const u16* pa1 = A  + (size_t)(m0 + ar + 64)*K + ac*8;
    const u16* pba = Wt + (size_t)(n0 + ar)*K       + ac*8;
    const u16* pbg = Wt + (size_t)(FFI + n0 + ar)*K + ac*8;
    const int nk = K >> 5;   // 10

    *(u16x8*)&As[0][ar*40 + ac*8]      = *(const u16x8*)pa0;
    *(u16x8*)&As[0][(ar+64)*40 + ac*8] = *(const u16x8*)pa1;
    *(u16x8*)&Ba[0][ar*40 + ac*8]      = *(const u16x8*)pba;
    *(u16x8*)&Bg[0][ar*40 + ac*8]      = *(const u16x8*)pbg;
    u16x8 ra0[2], ra1[2], rba[2], rbg[2];
    if (nk > 1) {
        ra0[1] = *(const u16x8*)(pa0 + 32);
        ra1[1] = *(const u16x8*)(pa1 + 32);
        rba[1] = *(const u16x8*)(pba + 32);
        rbg[1] = *(const u16x8*)(pbg + 32);
    }
    if (nk > 2) {
        ra0[0] = *(const u16x8*)(pa0 + 64);
        ra1[0] = *(const u16x8*)(pa1 + 64);
        rba[0] = *(const u16x8*)(pba + 64);
        rbg[0] = *(const u16x8*)(pbg + 64);
    }

    f32x4 aca[2][4] = {}, acg[2][4] = {};
    for (int i = 0; i < nk; ++i) {
        __syncthreads();
        const int cur = i & 1;
        if (i + 1 < nk) {
            const int s = (i + 1) & 1;
            *(u16x8*)&As[cur^1][ar*40 + ac*8]      = ra0[s];
            *(u16x8*)&As[cur^1][(ar+64)*40 + ac*8] = ra1[s];
            *(u16x8*)&Ba[cur^1][ar*40 + ac*8]      = rba[s];
            *(u16x8*)&Bg[cur^1][ar*40 + ac*8]      = rbg[s];
            if (i + 3 < nk) {
                const int f = (i + 3) & 1;
                ra0[f] = *(const u16x8*)(pa0 + 32*(i+3));
                ra1[f] = *(const u16x8*)(pa1 + 32*(i+3));
                rba[f] = *(const u16x8*)(pba + 32*(i+3));
                rbg[f] = *(const u16x8*)(pbg + 32*(i+3));
            }
        }
        bf16x8 a0 = *(const bf16x8*)&As[cur][(w*32      + fr)*40 + fg*8];
        bf16x8 a1 = *(const bf16x8*)&As[cur][(w*32 + 16 + fr)*40 + fg*8];
        #pragma unroll
        for (int nt = 0; nt < 4; ++nt) {
            bf16x8 ba = *(const bf16x8*)&Ba[cur][(nt*16 + fr)*40 + fg*8];
            bf16x8 bg = *(const bf16x8*)&Bg[cur][(nt*16 + fr)*40 + fg*8];
            aca[0][nt] = __builtin_amdgcn_mfma_f32_16x16x32_bf16(a0, ba, aca[0][nt], 0, 0, 0);
            aca[1][nt] = __builtin_amdgcn_mfma_f32_16x16x32_bf16(a1, ba, aca[1][nt], 0, 0, 0);
            acg[0][nt] = __builtin_amdgcn_mfma_f32_16x16x32_bf16(a0, bg, acg[0][nt], 0, 0, 0);
            acg[1][nt] = __builtin_amdgcn_mfma_f32_16x16x32_bf16(a1, bg, acg[1][nt], 0, 0, 0);
        }
    }
    #pragma unroll
    for (int at = 0; at < 2; ++at) {
        #pragma unroll
        for (int nt = 0; nt < 4; ++nt) {
            int gn = n0 + nt*16 + fr;
            float ba = b1[gn], bg = b1[FFI + gn];
            #pragma unroll
            for (int i = 0; i < 4; ++i) {
                int gm = m0 + w*32 + at*16 + fg*4 + i;
                float av = aca[at][nt][i] + ba;
                float gv = acg[at][nt][i] + bg;
                float gel = 0.5f*gv*(1.f + erff(gv*0.70710678118654752f));
                out[(size_t)gm*FFI + gn] = f2b(av*gel);
            }
        }
    }
}

// ------------------------------------------------- V transpose (per batch)
__global__ __launch_bounds__(256) void transpose_v(
    const u16* __restrict__ in, int istride, u16* __restrict__ out,
    int Ltok, int ostride)
{
    __shared__ u16 T[64*72];        // XOR-swizzled 16B chunks
    const int tid = threadIdx.x;
    const int c0 = blockIdx.x * 64;
    const int t0 = blockIdx.y * 64;
    const int b  = blockIdx.z;
    for (int e = tid; e < 512; e += 256) {
        int r = e >> 3, ch = e & 7;
        u16x8 val = {};
        if (t0 + r < Ltok)
            val = *(const u16x8*)(in + ((size_t)(b*Ltok + t0 + r))*istride + c0 + ch*8);
        *(u16x8*)&T[r*72 + (ch ^ (r & 7))*8] = val;
    }
    __syncthreads();
    for (int e = tid; e < 4096; e += 256) {
        int c = e >> 6, t = e & 63;
        u16 v = T[t*72 + (((c >> 3) ^ (t & 7))*8) + (c & 7)];
        out[((size_t)(b*Cch + c0 + c))*ostride + t0 + t] = v;
    }
}

// ------------------------------------------------------- MFMA flash attention
// Q prescaled (wq folded). No max-shift (scores O(1), exp cannot overflow).
// Mask post-exp; l via ones-row d=40 of V^T inside the PV MFMA.
__global__ __launch_bounds__(256) void flash_mfma(
    const u16* __restrict__ qb, int qstride,
    const u16* __restrict__ kb, int kstride,
    const u16* __restrict__ vt, int vstride,
    const u64* __restrict__ mbits, int nw,
    u16* __restrict__ out,        // [B*HW][320]
    int Lkv)
{
    __shared__ u16 QPs[64*72];    // Qs (stride 72), then Ps (stride 68)
    __shared__ u16 Ks[64*72];
    __shared__ u16 Vs[48*72];     // [d][key], row 40 = ones, 41..47 zero

    const int tid  = threadIdx.x;
    const int lane = tid & 63;
    const int w    = tid >> 6;
    const int col  = lane & 15;
    const int quad = lane >> 4;
    const int q0   = blockIdx.x * 64;
    const int h    = blockIdx.y;
    const int b    = blockIdx.z;
    const int ch   = tid & 7;
    const int r0   = tid >> 3;            // 0..31

    // stage Q tile (zero-padded d 40..63), stride 72
    {
        const u16* qT = qb + ((size_t)(b*HW + q0))*qstride + (size_t)h*DHEAD + ch*8;
        u16x8 v0 = {}, v1 = {};
        if (ch < 5) {
            v0 = *(const u16x8*)(qT + (size_t)r0*qstride);
            v1 = *(const u16x8*)(qT + (size_t)(r0+32)*qstride);
        }
        *(u16x8*)&QPs[r0*72 + ch*8]      = v0;
        *(u16x8*)&QPs[(r0+32)*72 + ch*8] = v1;
    }
    __syncthreads();
    const bf16x8 qa0 = *(const bf16x8*)&QPs[(w*16 + col)*72 +  0 + quad*8];
    const bf16x8 qa1 = *(const bf16x8*)&QPs[(w*16 + col)*72 + 32 + quad*8];

    // hoisted bases
    const u16* kT = kb + (size_t)b*Lkv*kstride + (size_t)h*DHEAD + ch*8;
    const bool kok = ch < 5;
    const u16* vT = vt + ((size_t)(b*Cch + h*DHEAD))*vstride + ch*8;
    const u64* mrow = mbits + ((size_t)(b*HW + q0 + w*16 + quad*4))*nw;

    f32x4 acc_o[3] = {};

    const int nkt = (Lkv + 63) / 64;
    for (int jt = 0; jt < nkt; ++jt) {
        const int j0 = jt*64;
        __syncthreads();                       // protect Ks/Vs (and Q reads, jt=0)
        {   // K tile rows r0, r0+32
            u16x8 v0 = {}, v1 = {};
            if (kok) {
                if (j0 + r0      < Lkv) v0 = *(const u16x8*)(kT + (size_t)(j0 + r0)*kstride);
                if (j0 + r0 + 32 < Lkv) v1 = *(const u16x8*)(kT + (size_t)(j0 + r0 + 32)*kstride);
            }
            *(u16x8*)&Ks[r0*72 + ch*8]      = v0;
            *(u16x8*)&Ks[(r0+32)*72 + ch*8] = v1;
        }
        {   // V^T tile rows 0..31 (all threads) + 32..47 (tid<128)
            u16x8 v0 = {};
            if (r0 < DHEAD) v0 = *(const u16x8*)(vT + (size_t)r0*vstride + j0);
            *(u16x8*)&Vs[r0*72 + ch*8] = v0;
            if (tid < 128) {
                int d1 = 32 + (tid >> 3);     // 32..47
                u16x8 v1 = {};
                if (d1 < DHEAD) v1 = *(const u16x8*)(vT + (size_t)d1*vstride + j0);
                else if (d1 == DHEAD) {
                    #pragma unroll
                    for (int z = 0; z < 8; ++z) v1[z] = 0x3F80;   // bf16 1.0
                }
                *(u16x8*)&Vs[d1*72 + ch*8] = v1;
            }
        }
        __syncthreads();

        // prefetch mask words (latency overlaps MFMA below)
        u64 mw[4];
        #pragma unroll
        for (int i = 0; i < 4; ++i) mw[i] = mrow[i*nw + jt];

        // S = Q K^T (prescaled)
        f32x4 s[4] = {};
        #pragma unroll
        for (int nt = 0; nt < 4; ++nt) {
            bf16x8 b0 = *(const bf16x8*)&Ks[(nt*16 + col)*72 +  0 + quad*8];
            bf16x8 b1 = *(const bf16x8*)&Ks[(nt*16 + col)*72 + 32 + quad*8];
            s[nt] = __builtin_amdgcn_mfma_f32_16x16x32_bf16(qa0, b0, s[nt], 0, 0, 0);
            s[nt] = __builtin_amdgcn_mfma_f32_16x16x32_bf16(qa1, b1, s[nt], 0, 0, 0);
        }

        // P = exp(S) (no shift), zero masked keys
        #pragma unroll
        for (int i = 0; i < 4; ++i) {
            #pragma unroll
            for (int nt = 0; nt < 4; ++nt) {
                float p = __expf(s[nt][i]);
                unsigned bits = (unsigned)(mw[i] >> (nt*16));
                s[nt][i] = ((bits >> col) & 1u) ? p : 0.f;
            }
        }

        // P -> LDS, stride 68, truncation to bf16
        #pragma unroll
        for (int nt = 0; nt < 4; ++nt)
            #pragma unroll
            for (int i = 0; i < 4; ++i)
                QPs[(w*16 + quad*4 + i)*68 + nt*16 + col] =
                    (u16)(__float_as_uint(s[nt][i]) >> 16);

        // O += P V   (col 40 accumulates l)
        bf16x8 pa0, pa1;
        __builtin_memcpy(&pa0, &QPs[(w*16 + col)*68 +  0 + quad*8], 16);
        __builtin_memcpy(&pa1, &QPs[(w*16 + col)*68 + 32 + quad*8], 16);
        #pragma unroll
        for (int nt = 0; nt < 3; ++nt) {
            bf16x8 vb0 = *(const bf16x8*)&Vs[(nt*16 + col)*72 +  0 + quad*8];
            bf16x8 vb1 = *(const bf16x8*)&Vs[(nt*16 + col)*72 + 32 + quad*8];
            acc_o[nt] = __builtin_amdgcn_mfma_f32_16x16x32_bf16(pa0, vb0, acc_o[nt], 0, 0, 0);
            acc_o[nt] = __builtin_amdgcn_mfma_f32_16x16x32_bf16(pa1, vb1, acc_o[nt], 0, 0, 0);
        }
    }

    // l_i lives in acc_o[2] at col 40 (lane col==8 of each 16-group)
    float inv_l[4];
    #pragma unroll
    for (int i = 0; i < 4; ++i)
        inv_l[i] = 1.f / __shfl(acc_o[2][i], (lane & 48) | 8);

    #pragma unroll
    for (int nt = 0; nt < 3; ++nt) {
        int d = nt*16 + col;
        if (d < DHEAD) {
            #pragma unroll
            for (int i = 0; i < 4; ++i) {
                int q = q0 + w*16 + quad*4 + i;
                out[((size_t)(b*HW + q))*Cch + h*DHEAD + d] = f2b(acc_o[nt][i] * inv_l[i]);
            }
        }
    }
}

// ---------------------------------------------------------------------------
extern "C" void kernel_launch(void* const* d_in, const int* in_sizes, int n_in,
                              void* d_out, int out_size, void* d_ws, size_t ws_size,
                              hipStream_t stream)
{
    const float* x        = (const float*)d_in[0];
    const float* context  = (const float*)d_in[1];
    const void*  vis_mask = d_in[2];
    const void*  v2t_mask = d_in[3];
    const float* gn_s     = (const float*)d_in[4];
    const float* gn_b     = (const float*)d_in[5];
    const float* proj_in_w= (const float*)d_in[6];
    const float* proj_in_b= (const float*)d_in[7];
    const float* n1_s     = (const float*)d_in[8];
    const float* n1_b     = (const float*)d_in[9];
    const float* wq1      = (const float*)d_in[10];
    const float* wk1      = (const float*)d_in[11];
    const float* wv1      = (const float*)d_in[12];
    const float* wo1      = (const float*)d_in[13];
    const float* bo1      = (const float*)d_in[14];
    const float* n2_s     = (const float*)d_in[15];
    const float* n2_b     = (const float*)d_in[16];
    const float* wq2      = (const float*)d_in[17];
    const float* wk2      = (const float*)d_in[18];
    const float* wv2      = (const float*)d_in[19];
    const float* wo2      = (const float*)d_in[20];
    const float* bo2      = (const float*)d_in[21];
    const float* n3_s     = (const float*)d_in[22];
    const float* n3_b     = (const float*)d_in[23];
    const float* ff_w1    = (const float*)d_in[24];
    const float* ff_b1    = (const float*)d_in[25];
    const float* ff_w2    = (const float*)d_in[26];
    const float* ff_b2    = (const float*)d_in[27];
    const float* pout_w   = (const float*)d_in[28];
    const float* pout_b   = (const float*)d_in[29];
    float* out = (float*)d_out;

    const size_t TOKC = (size_t)NTOK*Cch;        // 2,621,440
    float* ws   = (float*)d_ws;
    float* Hb   = ws;                            // fp32 residual spine
    u16*   QKV  = (u16*)(Hb + TOKC);             // [8192][960] packed, 3*TOKC
    u16*   Vt_g = QKV + 3*TOKC;                  // self V^T, TOKC
    u16*   G_bf = QKV;                           // FF reuse (4*TOKC)
    u16*   T0b  = Vt_g + TOKC;                   // LN/GN out, TOKC
    u16*   T1b  = T0b + TOKC;                    // attn out, TOKC
    u16*   Hb_bf= T1b + TOKC;                    // bf16 mirror post-FF, TOKC
    u16*   Wbf  = Hb_bf + TOKC;                  // 2,539,520 u16
    u64*   mb_vis = (u64*)(Wbf + 2539520);       // 8192*16 u64
    u64*   mb_v2t = mb_vis + 131072;             // 8192*2  u64
    u16*   ctx_bf = (u16*)(mb_v2t + 16384);      // 640*768 u16
    u16*   Kc_bf  = ctx_bf + MCTXP*CTXD;         // ctx K, 616*320 (pad 640)
    u16*   Vc_bf  = Kc_bf + 640*Cch;             // ctx V
    float* gnA    = (float*)(Vc_bf + 640*Cch);   // 8*320 floats
    float* gnB    = gnA + Bsz*Cch;

    u16* w_q1  = Wbf;                            // q1|k1|v1 contiguous [960][320]
    u16* w_k1  = Wbf +  102400;
    u16* w_v1  = Wbf +  204800;
    u16* w_pin = Wbf +  307200;
    u16* w_o1  = Wbf +  409600;
    u16* w_q2  = Wbf +  512000;
    u16* w_o2  = Wbf +  614400;
    u16* w_ff1 = Wbf +  716800;
    u16* w_ff2 = Wbf + 1536000;
    u16* w_po  = Wbf + 1945600;
    u16* w_k2  = Wbf + 2048000;                  // [320][768]
    u16* w_v2  = Wbf + 2293760;

    const float scale = 0.15811388300841897f;    // 1/sqrt(40)
    WPack pack;
    pack.w[0]  = { wq1,       w_q1,  Cch, Cch, 25,  scale };
    pack.w[1]  = { wk1,       w_k1,  Cch, Cch, 25,  1.f };
    pack.w[2]  = { wv1,       w_v1,  Cch, Cch, 25,  1.f };
    pack.w[3]  = { proj_in_w, w_pin, Cch, Cch, 25,  1.f };
    pack.w[4]  = { wo1,       w_o1,  Cch, Cch, 25,  1.f };
    pack.w[5]  = { wq2,       w_q2,  Cch, Cch, 25,  scale };
    pack.w[6]  = { wo2,       w_o2,  Cch, Cch, 25,  1.f };
    pack.w[7]  = { ff_w1,     w_ff1, Cch, 2*FFI, 200, 1.f };
    pack.w[8]  = { ff_w2,     w_ff2, FFI, Cch, 100, 1.f };
    pack.w[9]  = { pout_w,    w_po,  Cch, Cch, 25,  1.f };
    pack.w[10] = { wk2,       w_k2,  CTXD, Cch, 60, 1.f };
    pack.w[11] = { wv2,       w_v2,  CTXD, Cch, 60, 1.f };
    // total tiles = 7*25 + 200 + 100 + 25 + 60 + 60 = 620 = WT_TILES

    dim3 blk256(256);
    dim3 gTok(Cch/64, NTOK/128);                 // (5,64)
    dim3 gQKV(960/64, NTOK/128);                 // (15,64)
    dim3 gKV(Cch/64, MCTXP/64, 2);               // (5,10,2)
    dim3 gFF(FFI/64, NTOK/128);                  // (20,64)
    dim3 gFA(HW/64, HEADS, Bsz);                 // (16,8,8)
    dim3 gTrS(Cch/64, HW/64, Bsz);               // (5,16,8)
    dim3 gTrX(Cch/64, 2, Bsz);                   // (5,2,8)
    dim3 gGN(Cch/64, HW/64, Bsz);                // (5,16,8)

    // fused preamble: weight tiles | ctx | mask-bits(vis) | mask-bits(v2t)
    preamble<<<WT_TILES + CTXBLK + 4096, blk256, 0, stream>>>(
        pack, context, ctx_bf, vis_mask, v2t_mask, mb_vis, mb_v2t);

    gn_stats<<<Bsz*32, blk256, 0, stream>>>(x, gn_s, gn_b, gnA, gnB);
    gn_apply<<<gGN, blk256, 0, stream>>>(x, gnA, gnB, T0b);
    gemm_bf16<<<gTok, blk256, 0, stream>>>(T0b, w_pin, proj_in_b, nullptr, Hb, nullptr, NTOK, Cch, Cch);

    // --- self attention ---
    layernorm_kernel<<<NTOK/4, blk256, 0, stream>>>(Hb, n1_s, n1_b, T0b);
    gemm_bf16<<<gQKV, blk256, 0, stream>>>(T0b, w_q1, nullptr, nullptr, nullptr, QKV, NTOK, 960, Cch);
    transpose_v<<<gTrS, blk256, 0, stream>>>(QKV + 640, 960, Vt_g, HW, HW);
    flash_mfma<<<gFA, blk256, 0, stream>>>(QKV, 960, QKV + 320, 960, Vt_g, HW,
                                           mb_vis, 16, T1b, HW);
    gemm_bf16<<<gTok, blk256, 0, stream>>>(T1b, w_o1, bo1, Hb, Hb, nullptr, NTOK, Cch, Cch);

    // --- cross attention ---
    layernorm_kernel<<<NTOK/4, blk256, 0, stream>>>(Hb, n2_s, n2_b, T0b);
    gemm_bf16<<<gTok, blk256, 0, stream>>>(T0b, w_q2, nullptr, nullptr, nullptr, QKV, NTOK, Cch, Cch);
    ctx_kv_gemm<<<gKV, blk256, 0, stream>>>(ctx_bf, w_k2, w_v2, Kc_bf, Vc_bf);
    transpose_v<<<gTrX, blk256, 0, stream>>>(Vc_bf, Cch, Vt_g, CTXL, 128);
    flash_mfma<<<gFA, blk256, 0, stream>>>(QKV, Cch, Kc_bf, Cch, Vt_g, 128,
                                           mb_v2t, 2, T1b, CTXL);
    gemm_bf16<<<gTok, blk256, 0, stream>>>(T1b, w_o2, bo2, Hb, Hb, nullptr, NTOK, Cch, Cch);

    // --- GEGLU feed-forward ---
    layernorm_kernel<<<NTOK/4, blk256, 0, stream>>>(Hb, n3_s, n3_b, T0b);
    geglu_bf16<<<gFF, blk256, 0, stream>>>(T0b, w_ff1, ff_b1, G_bf, NTOK, Cch);
    gemm_bf16<<<gTok, blk256, 0, stream>>>(G_bf, w_ff2, ff_b2, Hb, nullptr, Hb_bf, NTOK, Cch, FFI);

    // --- proj_out + transpose + residual (fused) ---
    gemm_pout<<<gTok, blk256, 0, stream>>>(Hb_bf, w_po, pout_b, x, out, Cch);
}

// Round 14
// 407.008 us; speedup vs baseline: 1.9794x; 1.9794x over previous
//
#include <hip/hip_runtime.h>
#include <hip/hip_bf16.h>
#include <math.h>

// ---------------------------------------------------------------------------
// SpatialTransformer block. R13: depth-2 GEMM prefetch with STATIC register
// sets via unroll-by-2 K-loop (fixes R12 scratch-spill from dynamic reg
// indexing); tiled-transpose preamble kept.
// B=8, C=320, H=W=32 (HW=1024), HEADS=8, DHEAD=40, CTX=77x768, FF_INNER=1280.
// ---------------------------------------------------------------------------

#define Bsz   8
#define Cch   320
#define HW    1024
#define NTOK  (Bsz*HW)          // 8192
#define HEADS 8
#define DHEAD 40
#define CTXL  77
#define CTXD  768
#define FFI   1280
#define MCTX  (Bsz*CTXL)        // 616
#define MCTXP 640               // padded rows for ctx GEMM

typedef unsigned short u16;
typedef unsigned long long u64;
typedef __attribute__((ext_vector_type(8))) u16    u16x8;
typedef __attribute__((ext_vector_type(8))) __bf16 bf16x8;
typedef __attribute__((ext_vector_type(4))) float  f32x4;

__device__ inline u16 f2b(float f) {            // fp32 -> bf16 RNE
    unsigned u = __float_as_uint(f);
    return (u16)((u + 0x7FFFu + ((u >> 16) & 1u)) >> 16);
}

// ------------------------------------------- GroupNorm pass 1: statistics
__global__ __launch_bounds__(256) void gn_stats(
    const float* __restrict__ x, const float* __restrict__ scale,
    const float* __restrict__ bias, float* __restrict__ gnA,
    float* __restrict__ gnB)
{
    int blk = blockIdx.x;           // b*32 + g
    int b = blk >> 5, g = blk & 31;
    int tid = threadIdx.x;
    __shared__ float rs[256], rq[256];
    const float4* xg = (const float4*)(x + ((size_t)b*Cch + g*10)*HW);
    float s = 0.f, q = 0.f;
    #pragma unroll
    for (int i = 0; i < 10; ++i) {
        float4 v = xg[tid + i*256];
        s += v.x + v.y + v.z + v.w;
        q += v.x*v.x + v.y*v.y + v.z*v.z + v.w*v.w;
    }
    rs[tid] = s; rq[tid] = q; __syncthreads();
    for (int off = 128; off > 0; off >>= 1) {
        if (tid < off) { rs[tid] += rs[tid+off]; rq[tid] += rq[tid+off]; }
        __syncthreads();
    }
    if (tid < 10) {
        float mean = rs[0] * (1.f/10240.f);
        float var  = rq[0] * (1.f/10240.f) - mean*mean;
        float inv  = rsqrtf(var + 1e-6f);
        int ch = g*10 + tid;
        float a = inv * scale[ch];
        gnA[b*Cch + ch] = a;
        gnB[b*Cch + ch] = bias[ch] - mean*a;
    }
}

// ------------------------- GroupNorm pass 2: normalize + CHW->token-major
__global__ __launch_bounds__(256) void gn_apply(
    const float* __restrict__ x, const float* __restrict__ gnA,
    const float* __restrict__ gnB, u16* __restrict__ out)
{
    __shared__ u16 T[64*72];
    const int tid = threadIdx.x;
    const int c0 = blockIdx.x * 64;
    const int p0 = blockIdx.y * 64;
    const int b  = blockIdx.z;
    for (int e = tid; e < 512; e += 256) {
        int r = e >> 3, ch = e & 7;
        const float* src = x + ((size_t)(b*Cch + c0 + r))*HW + p0 + ch*8;
        float a  = gnA[b*Cch + c0 + r];
        float bb = gnB[b*Cch + c0 + r];
        float4 v0 = *(const float4*)src;
        float4 v1 = *(const float4*)(src + 4);
        u16x8 val;
        val[0] = f2b(v0.x*a + bb); val[1] = f2b(v0.y*a + bb);
        val[2] = f2b(v0.z*a + bb); val[3] = f2b(v0.w*a + bb);
        val[4] = f2b(v1.x*a + bb); val[5] = f2b(v1.y*a + bb);
        val[6] = f2b(v1.z*a + bb); val[7] = f2b(v1.w*a + bb);
        *(u16x8*)&T[r*72 + (ch ^ (r & 7))*8] = val;
    }
    __syncthreads();
    for (int e = tid; e < 4096; e += 256) {
        int p = e >> 6, c = e & 63;
        u16 v = T[c*72 + (((p >> 3) ^ (c & 7))*8) + (p & 7)];
        out[((size_t)(b*HW + p0 + p))*Cch + c0 + c] = v;
    }
}

// ------------------------------------------------------- LayerNorm -> bf16
__global__ __launch_bounds__(256) void layernorm_kernel(
    const float* __restrict__ in, const float* __restrict__ s,
    const float* __restrict__ bgain, u16* __restrict__ out)
{
    int t = blockIdx.x*4 + (threadIdx.x >> 6);
    int lane = threadIdx.x & 63;
    const float* row = in + (size_t)t*Cch;
    float v[5];
    float sum = 0.f, sq = 0.f;
    #pragma unroll
    for (int i = 0; i < 5; ++i) {
        v[i] = row[lane + 64*i];
        sum += v[i]; sq += v[i]*v[i];
    }
    #pragma unroll
    for (int off = 32; off > 0; off >>= 1) {
        sum += __shfl_xor(sum, off);
        sq  += __shfl_xor(sq,  off);
    }
    float mean = sum * (1.f/320.f);
    float var  = sq  * (1.f/320.f) - mean*mean;
    float inv  = rsqrtf(var + 1e-5f);
    u16* orow = out + (size_t)t*Cch;
    #pragma unroll
    for (int i = 0; i < 5; ++i) {
        int c = lane + 64*i;
        orow[c] = f2b((v[i]-mean)*inv*s[c] + bgain[c]);
    }
}

// ------------------------------- fused preamble: weights + ctx + mask bits
struct WDesc { const float* src; u16* dst; int K; int N; int tiles; float scl; };
struct WPack { WDesc w[12]; };

#define WT_TILES 620
#define CTXBLK   240     // 640*768 / 2048

__global__ __launch_bounds__(256) void preamble(
    WPack p, const float* __restrict__ ctxsrc, u16* __restrict__ ctxdst,
    const void* __restrict__ vis, const void* __restrict__ v2t,
    u64* __restrict__ bvis, u64* __restrict__ bv2t)
{
    __shared__ u16 T[64*72];
    int blk = blockIdx.x;
    int tid = threadIdx.x;
    if (blk < WT_TILES) {                      // tiled weight transpose
        int t = blk;
        #pragma unroll
        for (int i = 0; i < 12; ++i) {
            int nt = p.w[i].tiles;
            if (t < nt) {
                const int K = p.w[i].K, N = p.w[i].N;
                const int ntN = N >> 6;
                const int tk = t / ntN, tn = t - tk*ntN;
                const float scl = p.w[i].scl;
                const float* src = p.w[i].src;
                u16* dst = p.w[i].dst;
                for (int e = tid; e < 512; e += 256) {
                    int r = e >> 3, ch = e & 7;
                    const float* sp = src + (size_t)(tk*64 + r)*N + tn*64 + ch*8;
                    float4 v0 = *(const float4*)sp;
                    float4 v1 = *(const float4*)(sp + 4);
                    u16x8 val;
                    val[0] = f2b(v0.x*scl); val[1] = f2b(v0.y*scl);
                    val[2] = f2b(v0.z*scl); val[3] = f2b(v0.w*scl);
                    val[4] = f2b(v1.x*scl); val[5] = f2b(v1.y*scl);
                    val[6] = f2b(v1.z*scl); val[7] = f2b(v1.w*scl);
                    *(u16x8*)&T[r*72 + (ch ^ (r & 7))*8] = val;
                }
                __syncthreads();
                for (int e = tid; e < 4096; e += 256) {
                    int n = e >> 6, k = e & 63;
                    u16 v = T[k*72 + (((n >> 3) ^ (k & 7))*8) + (n & 7)];
                    dst[(size_t)(tn*64 + n)*K + tk*64 + k] = v;
                }
                return;
            }
            t -= nt;
        }
        return;
    }
    if (blk < WT_TILES + CTXBLK) {             // ctx fp32 -> bf16 (padded)
        int idx = (blk - WT_TILES)*2048 + tid*8;
        int r = idx / CTXD;
        u16x8 val = {};
        if (r < MCTX) {
            float4 v0 = *(const float4*)(ctxsrc + idx);
            float4 v1 = *(const float4*)(ctxsrc + idx + 4);
            val[0] = f2b(v0.x); val[1] = f2b(v0.y);
            val[2] = f2b(v0.z); val[3] = f2b(v0.w);
            val[4] = f2b(v1.x); val[5] = f2b(v1.y);
            val[6] = f2b(v1.z); val[7] = f2b(v1.w);
        }
        *(u16x8*)(ctxdst + idx) = val;
        return;
    }
    // mask -> bit words; dtype probed from vis[0..4096)
    __shared__ int any;
    if (tid == 0) any = 0;
    __syncthreads();
    const unsigned char* probe = (const unsigned char*)vis;
    for (int i = tid; i < 4096; i += 256)
        if ((i & 3) && probe[i]) any = 1;
    __syncthreads();
    const int isU8 = any;
    int mb = blk - WT_TILES - CTXBLK;          // 0..4095
    const void* mask; u64* bits; int Lkv, nw;
    if (mb < 2048) { mask = vis; bits = bvis; Lkv = HW;   nw = 16; }
    else           { mask = v2t; bits = bv2t; Lkv = CTXL; nw = 2; mb -= 2048; }
    const int wv = tid >> 6, lane = tid & 63;
    const int row = mb*4 + wv;
    const unsigned char* m8  = (const unsigned char*)mask;
    const int*           m32 = (const int*)mask;
    const size_t base = (size_t)row * Lkv;
    for (int w = 0; w < nw; ++w) {
        int j = w*64 + lane;
        bool on = (j < Lkv) && (isU8 ? (m8[base+j] != 0) : (m32[base+j] != 0));
        u64 word = __ballot(on);
        if (lane == 0) bits[(size_t)row*nw + w] = word;
    }
}

// --------- bf16 MFMA GEMM, unroll-2 K-loop, static 2-deep reg prefetch
// out[M,N] = A[M,K] @ Wt[N,K]^T (+bias)(+res). Block 128x64. nk must be even.
__global__ __launch_bounds__(256) void gemm_bf16(
    const u16* __restrict__ A, const u16* __restrict__ Wt,
    const float* __restrict__ bias, const float* __restrict__ res,
    float* __restrict__ out, u16* __restrict__ out_bf, int M, int N, int K)
{
    __shared__ u16 As[2][128*40];
    __shared__ u16 Bs[2][64*40];
    const int tid  = threadIdx.x;
    const int lane = tid & 63;
    const int w    = tid >> 6;
    const int m0   = blockIdx.y * 128;
    const int n0   = blockIdx.x * 64;
    const int fr   = lane & 15, fg = lane >> 4;
    const int ar   = tid >> 2, ac = tid & 3;

    const u16* pa0 = A  + (size_t)(m0 + ar)*K      + ac*8;
    const u16* pa1 = A  + (size_t)(m0 + ar + 64)*K + ac*8;
    const u16* pb  = Wt + (size_t)(n0 + ar)*K      + ac*8;
    const int nk = K >> 5;                      // 10, 24, or 40 — even

    *(u16x8*)&As[0][ar*40 + ac*8]      = *(const u16x8*)pa0;
    *(u16x8*)&As[0][(ar+64)*40 + ac*8] = *(const u16x8*)pa1;
    *(u16x8*)&Bs[0][ar*40 + ac*8]      = *(const u16x8*)pb;
    u16x8 xa0 = *(const u16x8*)(pa0 + 32);     // set X = odd chunks
    u16x8 xa1 = *(const u16x8*)(pa1 + 32);
    u16x8 xb  = *(const u16x8*)(pb  + 32);
    u16x8 ya0 = *(const u16x8*)(pa0 + 64);     // set Y = even chunks
    u16x8 ya1 = *(const u16x8*)(pa1 + 64);
    u16x8 yb  = *(const u16x8*)(pb  + 64);

    f32x4 acc[2][4] = {};
    for (int i = 0; i < nk; i += 2) {
        __syncthreads();
        // store chunk i+1 (set X) -> buf1; prefetch chunk i+3 into X
        *(u16x8*)&As[1][ar*40 + ac*8]      = xa0;
        *(u16x8*)&As[1][(ar+64)*40 + ac*8] = xa1;
        *(u16x8*)&Bs[1][ar*40 + ac*8]      = xb;
        if (i + 3 < nk) {
            xa0 = *(const u16x8*)(pa0 + 32*(i+3));
            xa1 = *(const u16x8*)(pa1 + 32*(i+3));
            xb  = *(const u16x8*)(pb  + 32*(i+3));
        }
        // compute chunk i from buf0
        {
            bf16x8 a0 = *(const bf16x8*)&As[0][(w*32      + fr)*40 + fg*8];
            bf16x8 a1 = *(const bf16x8*)&As[0][(w*32 + 16 + fr)*40 + fg*8];
            #pragma unroll
            for (int nt = 0; nt < 4; ++nt) {
                bf16x8 b = *(const bf16x8*)&Bs[0][(nt*16 + fr)*40 + fg*8];
                acc[0][nt] = __builtin_amdgcn_mfma_f32_16x16x32_bf16(a0, b, acc[0][nt], 0, 0, 0);
                acc[1][nt] = __builtin_amdgcn_mfma_f32_16x16x32_bf16(a1, b, acc[1][nt], 0, 0, 0);
            }
        }
        __syncthreads();
        // store chunk i+2 (set Y) -> buf0; prefetch chunk i+4 into Y
        if (i + 2 < nk) {
            *(u16x8*)&As[0][ar*40 + ac*8]      = ya0;
            *(u16x8*)&As[0][(ar+64)*40 + ac*8] = ya1;
            *(u16x8*)&Bs[0][ar*40 + ac*8]      = yb;
            if (i + 4 < nk) {
                ya0 = *(const u16x8*)(pa0 + 32*(i+4));
                ya1 = *(const u16x8*)(pa1 + 32*(i+4));
                yb  = *(const u16x8*)(pb  + 32*(i+4));
            }
        }
        // compute chunk i+1 from buf1
        {
            bf16x8 a0 = *(const bf16x8*)&As[1][(w*32      + fr)*40 + fg*8];
            bf16x8 a1 = *(const bf16x8*)&As[1][(w*32 + 16 + fr)*40 + fg*8];
            #pragma unroll
            for (int nt = 0; nt < 4; ++nt) {
                bf16x8 b = *(const bf16x8*)&Bs[1][(nt*16 + fr)*40 + fg*8];
                acc[0][nt] = __builtin_amdgcn_mfma_f32_16x16x32_bf16(a0, b, acc[0][nt], 0, 0, 0);
                acc[1][nt] = __builtin_amdgcn_mfma_f32_16x16x32_bf16(a1, b, acc[1][nt], 0, 0, 0);
            }
        }
    }
    #pragma unroll
    for (int at = 0; at < 2; ++at) {
        #pragma unroll
        for (int nt = 0; nt < 4; ++nt) {
            int gn = n0 + nt*16 + fr;
            float bv = bias ? bias[gn] : 0.f;
            #pragma unroll
            for (int i = 0; i < 4; ++i) {
                int gm = m0 + w*32 + at*16 + fg*4 + i;
                float v = acc[at][nt][i] + bv;
                if (res) v += res[(size_t)gm*N + gn];
                if (out) out[(size_t)gm*N + gn] = v;
                if (out_bf) out_bf[(size_t)gm*N + gn] = f2b(v);
            }
        }
    }
}

// ---- proj_out GEMM + transpose + residual, unroll-2 static prefetch
__global__ __launch_bounds__(256) void gemm_pout(
    const u16* __restrict__ A, const u16* __restrict__ Wt,
    const float* __restrict__ bias, const float* __restrict__ x,
    float* __restrict__ out, int K)
{
    __shared__ u16 As[2][128*40];
    __shared__ u16 Bs[2][64*40];
    const int tid  = threadIdx.x;
    const int lane = tid & 63;
    const int w    = tid >> 6;
    const int m0   = blockIdx.y * 128;
    const int n0   = blockIdx.x * 64;
    const int fr   = lane & 15, fg = lane >> 4;
    const int ar   = tid >> 2, ac = tid & 3;

    const u16* pa0 = A  + (size_t)(m0 + ar)*K      + ac*8;
    const u16* pa1 = A  + (size_t)(m0 + ar + 64)*K + ac*8;
    const u16* pb  = Wt + (size_t)(n0 + ar)*K      + ac*8;
    const int nk = K >> 5;                      // 10

    *(u16x8*)&As[0][ar*40 + ac*8]      = *(const u16x8*)pa0;
    *(u16x8*)&As[0][(ar+64)*40 + ac*8] = *(const u16x8*)pa1;
    *(u16x8*)&Bs[0][ar*40 + ac*8]      = *(const u16x8*)pb;
    u16x8 xa0 = *(const u16x8*)(pa0 + 32);
    u16x8 xa1 = *(const u16x8*)(pa1 + 32);
    u16x8 xb  = *(const u16x8*)(pb  + 32);
    u16x8 ya0 = *(const u16x8*)(pa0 + 64);
    u16x8 ya1 = *(const u16x8*)(pa1 + 64);
    u16x8 yb  = *(const u16x8*)(pb  + 64);

    f32x4 acc[2][4] = {};
    for (int i = 0; i < nk; i += 2) {
        __syncthreads();
        *(u16x8*)&As[1][ar*40 + ac*8]      = xa0;
        *(u16x8*)&As[1][(ar+64)*40 + ac*8] = xa1;
        *(u16x8*)&Bs[1][ar*40 + ac*8]      = xb;
        if (i + 3 < nk) {
            xa0 = *(const u16x8*)(pa0 + 32*(i+3));
            xa1 = *(const u16x8*)(pa1 + 32*(i+3));
            xb  = *(const u16x8*)(pb  + 32*(i+3));
        }
        {
            bf16x8 a0 = *(const bf16x8*)&As[0][(w*32      + fr)*40 + fg*8];
            bf16x8 a1 = *(const bf16x8*)&As[0][(w*32 + 16 + fr)*40 + fg*8];
            #pragma unroll
            for (int nt = 0; nt < 4; ++nt) {
                bf16x8 b = *(const bf16x8*)&Bs[0][(nt*16 + fr)*40 + fg*8];
                acc[0][nt] = __builtin_amdgcn_mfma_f32_16x16x32_bf16(a0, b, acc[0][nt], 0, 0, 0);
                acc[1][nt] = __builtin_amdgcn_mfma_f32_16x16x32_bf16(a1, b, acc[1][nt], 0, 0, 0);
            }
        }
        __syncthreads();
        if (i + 2 < nk) {
            *(u16x8*)&As[0][ar*40 + ac*8]      = ya0;
            *(u16x8*)&As[0][(ar+64)*40 + ac*8] = ya1;
            *(u16x8*)&Bs[0][ar*40 + ac*8]      = yb;
            if (i + 4 < nk) {
                ya0 = *(const u16x8*)(pa0 + 32*(i+4));
                ya1 = *(const u16x8*)(pa1 + 32*(i+4));
                yb  = *(const u16x8*)(pb  + 32*(i+4));
            }
        }
        {
            bf16x8 a0 = *(const bf16x8*)&As[1][(w*32      + fr)*40 + fg*8];
            bf16x8 a1 = *(const bf16x8*)&As[1][(w*32 + 16 + fr)*40 + fg*8];
            #pragma unroll
            for (int nt = 0; nt < 4; ++nt) {
                bf16x8 b = *(const bf16x8*)&Bs[1][(nt*16 + fr)*40 + fg*8];
                acc[0][nt] = __builtin_amdgcn_mfma_f32_16x16x32_bf16(a0, b, acc[0][nt], 0, 0, 0);
                acc[1][nt] = __builtin_amdgcn_mfma_f32_16x16x32_bf16(a1, b, acc[1][nt], 0, 0, 0);
            }
        }
    }
    #pragma unroll
    for (int at = 0; at < 2; ++at) {
        #pragma unroll
        for (int nt = 0; nt < 4; ++nt) {
            int gn = n0 + nt*16 + fr;
            float bv = bias[gn];
            int gm0 = m0 + w*32 + at*16 + fg*4;      // multiple of 4
            int b   = gm0 >> 10;
            int p   = gm0 & (HW-1);
            size_t o = ((size_t)(b*Cch + gn))*HW + p;
            f32x4 xv = *(const f32x4*)&x[o];
            f32x4 vv;
            #pragma unroll
            for (int i = 0; i < 4; ++i) vv[i] = acc[at][nt][i] + bv + xv[i];
            *(f32x4*)&out[o] = vv;
        }
    }
}

// ---- ctx K/V batched MFMA GEMM (bf16), unroll-2 static prefetch
__global__ __launch_bounds__(256) void ctx_kv_gemm(
    const u16* __restrict__ ctx, const u16* __restrict__ wk,
    const u16* __restrict__ wv, u16* __restrict__ kout, u16* __restrict__ vout)
{
    __shared__ u16 As[2][64*40];
    __shared__ u16 Bs[2][64*40];
    const int tid  = threadIdx.x;
    const int lane = tid & 63;
    const int w    = tid >> 6;
    const int m0   = blockIdx.y * 64;
    const int n0   = blockIdx.x * 64;
    const u16* Wt  = blockIdx.z ? wv : wk;
    u16* outp      = blockIdx.z ? vout : kout;
    const int fr   = lane & 15, fg = lane >> 4;
    const int ar   = tid >> 2, ac = tid & 3;

    const u16* pa = ctx + (size_t)(m0 + ar)*CTXD + ac*8;
    const u16* pb = Wt  + (size_t)(n0 + ar)*CTXD + ac*8;
    const int nk = CTXD >> 5;    // 24

    *(u16x8*)&As[0][ar*40 + ac*8] = *(const u16x8*)pa;
    *(u16x8*)&Bs[0][ar*40 + ac*8] = *(const u16x8*)pb;
    u16x8 xa = *(const u16x8*)(pa + 32);
    u16x8 xb = *(const u16x8*)(pb + 32);
    u16x8 ya = *(const u16x8*)(pa + 64);
    u16x8 yb = *(const u16x8*)(pb + 64);

    f32x4 acc[4] = {};
    for (int i = 0; i < nk; i += 2) {
        __syncthreads();
        *(u16x8*)&As[1][ar*40 + ac*8] = xa;
        *(u16x8*)&Bs[1][ar*40 + ac*8] = xb;
        if (i + 3 < nk) {
            xa = *(const u16x8*)(pa + 32*(i+3));
            xb = *(const u16x8*)(pb + 32*(i+3));
        }
        {
            bf16x8 a = *(const bf16x8*)&As[0][(w*16 + fr)*40 + fg*8];
            #pragma unroll
            for (int nt = 0; nt < 4; ++nt) {
                bf16x8 b = *(const bf16x8*)&Bs[0][(nt*16 + fr)*40 + fg*8];
                acc[nt] = __builtin_amdgcn_mfma_f32_16x16x32_bf16(a, b, acc[nt], 0, 0, 0);
            }
        }
        __syncthreads();
        if (i + 2 < nk) {
            *(u16x8*)&As[0][ar*40 + ac*8] = ya;
            *(u16x8*)&Bs[0][ar*40 + ac*8] = yb;
            if (i + 4 < nk) {
                ya = *(const u16x8*)(pa + 32*(i+4));
                yb = *(const u16x8*)(pb + 32*(i+4));
            }
        }
        {
            bf16x8 a = *(const bf16x8*)&As[1][(w*16 + fr)*40 + fg*8];
            #pragma unroll
            for (int nt = 0; nt < 4; ++nt) {
                bf16x8 b = *(const bf16x8*)&Bs[1][(nt*16 + fr)*40 + fg*8];
                acc[nt] = __builtin_amdgcn_mfma_f32_16x16x32_bf16(a, b, acc[nt], 0, 0, 0);
            }
        }
    }
    #pragma unroll
    for (int nt = 0; nt < 4; ++nt) {
        int gn = n0 + nt*16 + fr;
        #pragma unroll
        for (int i = 0; i < 4; ++i) {
            int gm = m0 + w*16 + fg*4 + i;
            if (gm < MCTX)
                outp[(size_t)gm*Cch + gn] = f2b(acc[nt][i]);
        }
    }
}

// ---- GEGLU fused MFMA GEMM (bf16), unroll-2 static prefetch
__global__ __launch_bounds__(256) void geglu_bf16(
    const u16* __restrict__ A, const u16* __restrict__ Wt,
    const float* __restrict__ b1, u16* __restrict__ out, int M, int K)
{
    __shared__ u16 As[2][128*40];
    __shared__ u16 Ba[2][64*40];
    __shared__ u16 Bg[2][64*40];
    const int tid  = threadIdx.x;
    const int lane = tid & 63;
    const int w    = tid >> 6;
    const int m0   = blockIdx.y * 128;
    const int n0   = blockIdx.x * 64;
    const int fr   = lane & 15, fg = lane >> 4;
    const int ar   = tid >> 2, ac = tid & 3;

    const u16* pa0 = A  + (size_t)(m0 + ar)*K      + ac*8;
    const u16* pa1 = A  + (size_t)(m0 + ar + 64)*K + ac*8;
    const u16* pba = Wt + (size_t)(n0 + ar)*K       + ac*8;
    const u16* pbg = Wt + (size_t)(FFI + n0 + ar)*K + ac*8;
    const int nk = K >> 5;   // 10

    *(u16x8*)&As[0][ar*40 + ac*8]      = *(const u16x8*)pa0;
    *(u16x8*)&As[0][(ar+64)*40 + ac*8] = *(const u16x8*)pa1;
    *(u16x8*)&Ba[0][ar*40 + ac*8]      = *(const u16x8*)pba;
    *(u16x8*)&Bg[0][ar*40 + ac*8]      = *(const u16x8*)pbg;
    u16x8 xa0 = *(const u16x8*)(pa0 + 32);
    u16x8 xa1 = *(const u16x8*)(pa1 + 32);
    u16x8 xba = *(const u16x8*)(pba + 32);
    u16x8 xbg = *(const u16x8*)(pbg + 32);
    u16x8 ya0 = *(const u16x8*)(pa0 + 64);
    u16x8 ya1 = *(const u16x8*)(pa1 + 64);
    u16x8 yba = *(const u16x8*)(pba + 64);
    u16x8 ybg = *(const u16x8*)(pbg + 64);

    f32x4 aca[2][4] = {}, acg[2][4] = {};
    for (int i = 0; i < nk; i += 2) {
        __syncthreads();
        *(u16x8*)&As[1][ar*40 + ac*8]      = xa0;
        *(u16x8*)&As[1][(ar+64)*40 + ac*8] = xa1;
        *(u16x8*)&Ba[1][ar*40 + ac*8]      = xba;
        *(u16x8*)&Bg[1][ar*40 + ac*8]      = xbg;
        if (i + 3 < nk) {
            xa0 = *(const u16x8*)(pa0 + 32*(i+3));
            xa1 = *(const u16x8*)(pa1 + 32*(i+3));
            xba = *(const u16x8*)(pba + 32*(i+3));
            xbg = *(const u16x8*)(pbg + 32*(i+3));
        }
        {
            bf16x8 a0 = *(const bf16x8*)&As[0][(w*32      + fr)*40 + fg*8];
            bf16x8 a1 = *(const bf16x8*)&As[0][(w*32 + 16 + fr)*40 + fg*8];
            #pragma unroll
            for (int nt = 0; nt < 4; ++nt) {
                bf16x8 ba = *(const bf16x8*)&Ba[0][(nt*16 + fr)*40 + fg*8];
                bf16x8 bg = *(const bf16x8*)&Bg[0][(nt*16 + fr)*40 + fg*8];
                aca[0][nt] = __builtin_amdgcn_mfma_f32_16x16x32_bf16(a0, ba, aca[0][nt], 0, 0, 0);
                aca[1][nt] = __builtin_amdgcn_mfma_f32_16x16x32_bf16(a1, ba, aca[1][nt], 0, 0, 0);
                acg[0][nt] = __builtin_amdgcn_mfma_f32_16x16x32_bf16(a0, bg, acg[0][nt], 0, 0, 0);
                acg[1][nt] = __builtin_amdgcn_mfma_f32_16x16x32_bf16(a1, bg, acg[1][nt], 0, 0, 0);
            }
        }
        __syncthreads();
        if (i + 2 < nk) {
            *(u16x8*)&As[0][ar*40 + ac*8]      = ya0;
            *(u16x8*)&As[0][(ar+64)*40 + ac*8] = ya1;
            *(u16x8*)&Ba[0][ar*40 + ac*8]      = yba;
            *(u16x8*)&Bg[0][ar*40 + ac*8]      = ybg;
            if (i + 4 < nk) {
                ya0 = *(const u16x8*)(pa0 + 32*(i+4));
                ya1 = *(const u16x8*)(pa1 + 32*(i+4));
                yba = *(const u16x8*)(pba + 32*(i+4));
                ybg = *(const u16x8*)(pbg + 32*(i+4));
            }
        }
        {
            bf16x8 a0 = *(const bf16x8*)&As[1][(w*32      + fr)*40 + fg*8];
            bf16x8 a1 = *(const bf16x8*)&As[1][(w*32 + 16 + fr)*40 + fg*8];
            #pragma unroll
            for (int nt = 0; nt < 4; ++nt) {
                bf16x8 ba = *(const bf16x8*)&Ba[1][(nt*16 + fr)*40 + fg*8];
                bf16x8 bg = *(const bf16x8*)&Bg[1][(nt*16 + fr)*40 + fg*8];
                aca[0][nt] = __builtin_amdgcn_mfma_f32_16x16x32_bf16(a0, ba, aca[0][nt], 0, 0, 0);
                aca[1][nt] = __builtin_amdgcn_mfma_f32_16x16x32_bf16(a1, ba, aca[1][nt], 0, 0, 0);
                acg[0][nt] = __builtin_amdgcn_mfma_f32_16x16x32_bf16(a0, bg, acg[0][nt], 0, 0, 0);
                acg[1][nt] = __builtin_amdgcn_mfma_f32_16x16x32_bf16(a1, bg, acg[1][nt], 0, 0, 0);
            }
        }
    }
    #pragma unroll
    for (int at = 0; at < 2; ++at) {
        #pragma unroll
        for (int nt = 0; nt < 4; ++nt) {
            int gn = n0 + nt*16 + fr;
            float ba = b1[gn], bg = b1[FFI + gn];
            #pragma unroll
            for (int i = 0; i < 4; ++i) {
                int gm = m0 + w*32 + at*16 + fg*4 + i;
                float av = aca[at][nt][i] + ba;
                float gv = acg[at][nt][i] + bg;
                float gel = 0.5f*gv*(1.f + erff(gv*0.70710678118654752f));
                out[(size_t)gm*FFI + gn] = f2b(av*gel);
            }
        }
    }
}

// ------------------------------------------------- V transpose (per batch)
__global__ __launch_bounds__(256) void transpose_v(
    const u16* __restrict__ in, int istride, u16* __restrict__ out,
    int Ltok, int ostride)
{
    __shared__ u16 T[64*72];        // XOR-swizzled 16B chunks
    const int tid = threadIdx.x;
    const int c0 = blockIdx.x * 64;
    const int t0 = blockIdx.y * 64;
    const int b  = blockIdx.z;
    for (int e = tid; e < 512; e += 256) {
        int r = e >> 3, ch = e & 7;
        u16x8 val = {};
        if (t0 + r < Ltok)
            val = *(const u16x8*)(in + ((size_t)(b*Ltok + t0 + r))*istride + c0 + ch*8);
        *(u16x8*)&T[r*72 + (ch ^ (r & 7))*8] = val;
    }
    __syncthreads();
    for (int e = tid; e < 4096; e += 256) {
        int c = e >> 6, t = e & 63;
        u16 v = T[t*72 + (((c >> 3) ^ (t & 7))*8) + (c & 7)];
        out[((size_t)(b*Cch + c0 + c))*ostride + t0 + t] = v;
    }
}

// ------------------------------------------------------- MFMA flash attention
__global__ __launch_bounds__(256) void flash_mfma(
    const u16* __restrict__ qb, int qstride,
    const u16* __restrict__ kb, int kstride,
    const u16* __restrict__ vt, int vstride,
    const u64* __restrict__ mbits, int nw,
    u16* __restrict__ out,        // [B*HW][320]
    int Lkv)
{
    __shared__ u16 QPs[64*72];    // Qs (stride 72), then Ps (stride 68)
    __shared__ u16 Ks[64*72];
    __shared__ u16 Vs[48*72];     // [d][key], row 40 = ones, 41..47 zero

    const int tid  = threadIdx.x;
    const int lane = tid & 63;
    const int w    = tid >> 6;
    const int col  = lane & 15;
    const int quad = lane >> 4;
    const int q0   = blockIdx.x * 64;
    const int h    = blockIdx.y;
    const int b    = blockIdx.z;
    const int ch   = tid & 7;
    const int r0   = tid >> 3;            // 0..31

    // stage Q tile (zero-padded d 40..63), stride 72
    {
        const u16* qT = qb + ((size_t)(b*HW + q0))*qstride + (size_t)h*DHEAD + ch*8;
        u16x8 v0 = {}, v1 = {};
        if (ch < 5) {
            v0 = *(const u16x8*)(qT + (size_t)r0*qstride);
            v1 = *(const u16x8*)(qT + (size_t)(r0+32)*qstride);
        }
        *(u16x8*)&QPs[r0*72 + ch*8]      = v0;
        *(u16x8*)&QPs[(r0+32)*72 + ch*8] = v1;
    }
    __syncthreads();
    const bf16x8 qa0 = *(const bf16x8*)&QPs[(w*16 + col)*72 +  0 + quad*8];
    const bf16x8 qa1 = *(const bf16x8*)&QPs[(w*16 + col)*72 + 32 + quad*8];

    // hoisted bases
    const u16* kT = kb + (size_t)b*Lkv*kstride + (size_t)h*DHEAD + ch*8;
    const bool kok = ch < 5;
    const u16* vT = vt + ((size_t)(b*Cch + h*DHEAD))*vstride + ch*8;
    const u64* mrow = mbits + ((size_t)(b*HW + q0 + w*16 + quad*4))*nw;

    f32x4 acc_o[3] = {};

    const int nkt = (Lkv + 63) / 64;
    for (int jt = 0; jt < nkt; ++jt) {
        const int j0 = jt*64;
        __syncthreads();                       // protect Ks/Vs (and Q reads, jt=0)
        {   // K tile rows r0, r0+32
            u16x8 v0 = {}, v1 = {};
            if (kok) {
                if (j0 + r0      < Lkv) v0 = *(const u16x8*)(kT + (size_t)(j0 + r0)*kstride);
                if (j0 + r0 + 32 < Lkv) v1 = *(const u16x8*)(kT + (size_t)(j0 + r0 + 32)*kstride);
            }
            *(u16x8*)&Ks[r0*72 + ch*8]      = v0;
            *(u16x8*)&Ks[(r0+32)*72 + ch*8] = v1;
        }
        {   // V^T tile rows 0..31 (all threads) + 32..47 (tid<128)
            u16x8 v0 = {};
            if (r0 < DHEAD) v0 = *(const u16x8*)(vT + (size_t)r0*vstride + j0);
            *(u16x8*)&Vs[r0*72 + ch*8] = v0;
            if (tid < 128) {
                int d1 = 32 + (tid >> 3);     // 32..47
                u16x8 v1 = {};
                if (d1 < DHEAD) v1 = *(const u16x8*)(vT + (size_t)d1*vstride + j0);
                else if (d1 == DHEAD) {
                    #pragma unroll
                    for (int z = 0; z < 8; ++z) v1[z] = 0x3F80;   // bf16 1.0
                }
                *(u16x8*)&Vs[d1*72 + ch*8] = v1;
            }
        }
        __syncthreads();

        // prefetch mask words (latency overlaps MFMA below)
        u64 mw[4];
        #pragma unroll
        for (int i = 0; i < 4; ++i) mw[i] = mrow[i*nw + jt];

        // S = Q K^T (prescaled)
        f32x4 s[4] = {};
        #pragma unroll
        for (int nt = 0; nt < 4; ++nt) {
            bf16x8 b0 = *(const bf16x8*)&Ks[(nt*16 + col)*72 +  0 + quad*8];
            bf16x8 b1 = *(const bf16x8*)&Ks[(nt*16 + col)*72 + 32 + quad*8];
            s[nt] = __builtin_amdgcn_mfma_f32_16x16x32_bf16(qa0, b0, s[nt], 0, 0, 0);
            s[nt] = __builtin_amdgcn_mfma_f32_16x16x32_bf16(qa1, b1, s[nt], 0, 0, 0);
        }

        // P = exp(S) (no shift), zero masked keys
        #pragma unroll
        for (int i = 0; i < 4; ++i) {
            #pragma unroll
            for (int nt = 0; nt < 4; ++nt) {
                float p = __expf(s[nt][i]);
                unsigned bits = (unsigned)(mw[i] >> (nt*16));
                s[nt][i] = ((bits >> col) & 1u) ? p : 0.f;
            }
        }

        // P -> LDS, stride 68, truncation to bf16
        #pragma unroll
        for (int nt = 0; nt < 4; ++nt)
            #pragma unroll
            for (int i = 0; i < 4; ++i)
                QPs[(w*16 + quad*4 + i)*68 + nt*16 + col] =
                    (u16)(__float_as_uint(s[nt][i]) >> 16);

        // O += P V   (col 40 accumulates l)
        bf16x8 pa0, pa1;
        __builtin_memcpy(&pa0, &QPs[(w*16 + col)*68 +  0 + quad*8], 16);
        __builtin_memcpy(&pa1, &QPs[(w*16 + col)*68 + 32 + quad*8], 16);
        #pragma unroll
        for (int nt = 0; nt < 3; ++nt) {
            bf16x8 vb0 = *(const bf16x8*)&Vs[(nt*16 + col)*72 +  0 + quad*8];
            bf16x8 vb1 = *(const bf16x8*)&Vs[(nt*16 + col)*72 + 32 + quad*8];
            acc_o[nt] = __builtin_amdgcn_mfma_f32_16x16x32_bf16(pa0, vb0, acc_o[nt], 0, 0, 0);
            acc_o[nt] = __builtin_amdgcn_mfma_f32_16x16x32_bf16(pa1, vb1, acc_o[nt], 0, 0, 0);
        }
    }

    // l_i lives in acc_o[2] at col 40 (lane col==8 of each 16-group)
    float inv_l[4];
    #pragma unroll
    for (int i = 0; i < 4; ++i)
        inv_l[i] = 1.f / __shfl(acc_o[2][i], (lane & 48) | 8);

    #pragma unroll
    for (int nt = 0; nt < 3; ++nt) {
        int d = nt*16 + col;
        if (d < DHEAD) {
            #pragma unroll
            for (int i = 0; i < 4; ++i) {
                int q = q0 + w*16 + quad*4 + i;
                out[((size_t)(b*HW + q))*Cch + h*DHEAD + d] = f2b(acc_o[nt][i] * inv_l[i]);
            }
        }
    }
}

// ---------------------------------------------------------------------------
extern "C" void kernel_launch(void* const* d_in, const int* in_sizes, int n_in,
                              void* d_out, int out_size, void* d_ws, size_t ws_size,
                              hipStream_t stream)
{
    const float* x        = (const float*)d_in[0];
    const float* context  = (const float*)d_in[1];
    const void*  vis_mask = d_in[2];
    const void*  v2t_mask = d_in[3];
    const float* gn_s     = (const float*)d_in[4];
    const float* gn_b     = (const float*)d_in[5];
    const float* proj_in_w= (const float*)d_in[6];
    const float* proj_in_b= (const float*)d_in[7];
    const float* n1_s     = (const float*)d_in[8];
    const float* n1_b     = (const float*)d_in[9];
    const float* wq1      = (const float*)d_in[10];
    const float* wk1      = (const float*)d_in[11];
    const float* wv1      = (const float*)d_in[12];
    const float* wo1      = (const float*)d_in[13];
    const float* bo1      = (const float*)d_in[14];
    const float* n2_s     = (const float*)d_in[15];
    const float* n2_b     = (const float*)d_in[16];
    const float* wq2      = (const float*)d_in[17];
    const float* wk2      = (const float*)d_in[18];
    const float* wv2      = (const float*)d_in[19];
    const float* wo2      = (const float*)d_in[20];
    const float* bo2      = (const float*)d_in[21];
    const float* n3_s     = (const float*)d_in[22];
    const float* n3_b     = (const float*)d_in[23];
    const float* ff_w1    = (const float*)d_in[24];
    const float* ff_b1    = (const float*)d_in[25];
    const float* ff_w2    = (const float*)d_in[26];
    const float* ff_b2    = (const float*)d_in[27];
    const float* pout_w   = (const float*)d_in[28];
    const float* pout_b   = (const float*)d_in[29];
    float* out = (float*)d_out;

    const size_t TOKC = (size_t)NTOK*Cch;        // 2,621,440
    float* ws   = (float*)d_ws;
    float* Hb   = ws;                            // fp32 residual spine
    u16*   QKV  = (u16*)(Hb + TOKC);             // [8192][960] packed, 3*TOKC
    u16*   Vt_g = QKV + 3*TOKC;                  // self V^T, TOKC
    u16*   G_bf = QKV;                           // FF reuse (4*TOKC)
    u16*   T0b  = Vt_g + TOKC;                   // LN/GN out, TOKC
    u16*   T1b  = T0b + TOKC;                    // attn out, TOKC
    u16*   Hb_bf= T1b + TOKC;                    // bf16 mirror post-FF, TOKC
    u16*   Wbf  = Hb_bf + TOKC;                  // 2,539,520 u16
    u64*   mb_vis = (u64*)(Wbf + 2539520);       // 8192*16 u64
    u64*   mb_v2t = mb_vis + 131072;             // 8192*2  u64
    u16*   ctx_bf = (u16*)(mb_v2t + 16384);      // 640*768 u16
    u16*   Kc_bf  = ctx_bf + MCTXP*CTXD;         // ctx K, 616*320 (pad 640)
    u16*   Vc_bf  = Kc_bf + 640*Cch;             // ctx V
    float* gnA    = (float*)(Vc_bf + 640*Cch);   // 8*320 floats
    float* gnB    = gnA + Bsz*Cch;

    u16* w_q1  = Wbf;                            // q1|k1|v1 contiguous [960][320]
    u16* w_k1  = Wbf +  102400;
    u16* w_v1  = Wbf +  204800;
    u16* w_pin = Wbf +  307200;
    u16* w_o1  = Wbf +  409600;
    u16* w_q2  = Wbf +  512000;
    u16* w_o2  = Wbf +  614400;
    u16* w_ff1 = Wbf +  716800;
    u16* w_ff2 = Wbf + 1536000;
    u16* w_po  = Wbf + 1945600;
    u16* w_k2  = Wbf + 2048000;                  // [320][768]
    u16* w_v2  = Wbf + 2293760;

    const float scale = 0.15811388300841897f;    // 1/sqrt(40)
    WPack pack;
    pack.w[0]  = { wq1,       w_q1,  Cch, Cch, 25,  scale };
    pack.w[1]  = { wk1,       w_k1,  Cch, Cch, 25,  1.f };
    pack.w[2]  = { wv1,       w_v1,  Cch, Cch, 25,  1.f };
    pack.w[3]  = { proj_in_w, w_pin, Cch, Cch, 25,  1.f };
    pack.w[4]  = { wo1,       w_o1,  Cch, Cch, 25,  1.f };
    pack.w[5]  = { wq2,       w_q2,  Cch, Cch, 25,  scale };
    pack.w[6]  = { wo2,       w_o2,  Cch, Cch, 25,  1.f };
    pack.w[7]  = { ff_w1,     w_ff1, Cch, 2*FFI, 200, 1.f };
    pack.w[8]  = { ff_w2,     w_ff2, FFI, Cch, 100, 1.f };
    pack.w[9]  = { pout_w,    w_po,  Cch, Cch, 25,  1.f };
    pack.w[10] = { wk2,       w_k2,  CTXD, Cch, 60, 1.f };
    pack.w[11] = { wv2,       w_v2,  CTXD, Cch, 60, 1.f };
    // total tiles = 7*25 + 200 + 100 + 25 + 60 + 60 = 620 = WT_TILES

    dim3 blk256(256);
    dim3 gTok(Cch/64, NTOK/128);                 // (5,64)
    dim3 gQKV(960/64, NTOK/128);                 // (15,64)
    dim3 gKV(Cch/64, MCTXP/64, 2);               // (5,10,2)
    dim3 gFF(FFI/64, NTOK/128);                  // (20,64)
    dim3 gFA(HW/64, HEADS, Bsz);                 // (16,8,8)
    dim3 gTrS(Cch/64, HW/64, Bsz);               // (5,16,8)
    dim3 gTrX(Cch/64, 2, Bsz);                   // (5,2,8)
    dim3 gGN(Cch/64, HW/64, Bsz);                // (5,16,8)

    // fused preamble: weight tiles | ctx | mask-bits(vis) | mask-bits(v2t)
    preamble<<<WT_TILES + CTXBLK + 4096, blk256, 0, stream>>>(
        pack, context, ctx_bf, vis_mask, v2t_mask, mb_vis, mb_v2t);

    gn_stats<<<Bsz*32, blk256, 0, stream>>>(x, gn_s, gn_b, gnA, gnB);
    gn_apply<<<gGN, blk256, 0, stream>>>(x, gnA, gnB, T0b);
    gemm_bf16<<<gTok, blk256, 0, stream>>>(T0b, w_pin, proj_in_b, nullptr, Hb, nullptr, NTOK, Cch, Cch);

    // --- self attention ---
    layernorm_kernel<<<NTOK/4, blk256, 0, stream>>>(Hb, n1_s, n1_b, T0b);
    gemm_bf16<<<gQKV, blk256, 0, stream>>>(T0b, w_q1, nullptr, nullptr, nullptr, QKV, NTOK, 960, Cch);
    transpose_v<<<gTrS, blk256, 0, stream>>>(QKV + 640, 960, Vt_g, HW, HW);
    flash_mfma<<<gFA, blk256, 0, stream>>>(QKV, 960, QKV + 320, 960, Vt_g, HW,
                                           mb_vis, 16, T1b, HW);
    gemm_bf16<<<gTok, blk256, 0, stream>>>(T1b, w_o1, bo1, Hb, Hb, nullptr, NTOK, Cch, Cch);

    // --- cross attention ---
    layernorm_kernel<<<NTOK/4, blk256, 0, stream>>>(Hb, n2_s, n2_b, T0b);
    gemm_bf16<<<gTok, blk256, 0, stream>>>(T0b, w_q2, nullptr, nullptr, nullptr, QKV, NTOK, Cch, Cch);
    ctx_kv_gemm<<<gKV, blk256, 0, stream>>>(ctx_bf, w_k2, w_v2, Kc_bf, Vc_bf);
    transpose_v<<<gTrX, blk256, 0, stream>>>(Vc_bf, Cch, Vt_g, CTXL, 128);
    flash_mfma<<<gFA, blk256, 0, stream>>>(QKV, Cch, Kc_bf, Cch, Vt_g, 128,
                                           mb_v2t, 2, T1b, CTXL);
    gemm_bf16<<<gTok, blk256, 0, stream>>>(T1b, w_o2, bo2, Hb, Hb, nullptr, NTOK, Cch, Cch);

    // --- GEGLU feed-forward ---
    layernorm_kernel<<<NTOK/4, blk256, 0, stream>>>(Hb, n3_s, n3_b, T0b);
    geglu_bf16<<<gFF, blk256, 0, stream>>>(T0b, w_ff1, ff_b1, G_bf, NTOK, Cch);
    gemm_bf16<<<gTok, blk256, 0, stream>>>(G_bf, w_ff2, ff_b2, Hb, nullptr, Hb_bf, NTOK, Cch, FFI);

    // --- proj_out + transpose + residual (fused) ---
    gemm_pout<<<gTok, blk256, 0, stream>>>(Hb_bf, w_po, pout_b, x, out, Cch);
}